// Round 6
// baseline (513.525 us; speedup 1.0000x reference)
//
#include <hip/hip_runtime.h>
#include <hip/hip_bf16.h>

#define IN_DIM 256
#define HC     64    // H*C for layer 1
#define OUT_DIM 40
#define NEG    0.2f

#define NPB    16    // nodes per bucket (power of 2)
#define NPB_SH 4
#define S2_CAP 2048  // staged entries per bucket (mean ~280 for deg~17)
#define NPART  8     // XCD partitions

typedef __bf16 bf16x8 __attribute__((ext_vector_type(8)));
typedef float  f32x4  __attribute__((ext_vector_type(4)));

__device__ inline float lrelu(float v) { return fmaxf(v, NEG * v); }  // NEG<1

// ---------------- zero deg / pbcnt ----------------
__global__ void zero_kernel(int* __restrict__ deg, int* __restrict__ pbcnt,
                            int n, int npb) {
  int i = blockIdx.x * blockDim.x + threadIdx.x;
  if (i < n) deg[i] = 0;
  if (i < npb) pbcnt[i] = 0;
}

// ---------------- CSR build: node histogram + per-(partition,bucket) histogram ----------------
__global__ void count_kernel(const int* __restrict__ ei, int* __restrict__ deg,
                             int* __restrict__ pbcnt, int E, int ET, int nbuck) {
  int e = blockIdx.x * blockDim.x + threadIdx.x;
  if (e >= ET) return;
  int d = (e < E) ? ei[E + e] : (e - E);   // self-loops appended
  atomicAdd(&deg[d], 1);
  atomicAdd(&pbcnt[(blockIdx.x & (NPART - 1)) * nbuck + (d >> NPB_SH)], 1);
}

// ---------------- CSR build: 3-phase exclusive scan (1024 elems/block) ----------------
__global__ void scan1_kernel(const int* __restrict__ deg, int* __restrict__ offs,
                             int* __restrict__ partial, int n) {
  __shared__ int sm[256];
  int tid = threadIdx.x;
  int base = blockIdx.x * 1024 + tid * 4;
  int v0 = 0, v1 = 0, v2 = 0, v3 = 0;
  if (base + 0 < n) v0 = deg[base + 0];
  if (base + 1 < n) v1 = deg[base + 1];
  if (base + 2 < n) v2 = deg[base + 2];
  if (base + 3 < n) v3 = deg[base + 3];
  int t = v0 + v1 + v2 + v3;
  sm[tid] = t; __syncthreads();
  for (int o = 1; o < 256; o <<= 1) {
    int x = (tid >= o) ? sm[tid - o] : 0;
    __syncthreads();
    sm[tid] += x;
    __syncthreads();
  }
  int excl = sm[tid] - t;
  if (base + 0 < n) offs[base + 0] = excl;
  if (base + 1 < n) offs[base + 1] = excl + v0;
  if (base + 2 < n) offs[base + 2] = excl + v0 + v1;
  if (base + 3 < n) offs[base + 3] = excl + v0 + v1 + v2;
  if (tid == 255) partial[blockIdx.x] = sm[255];
}

__global__ void scan2_kernel(int* __restrict__ partial, int nb) {
  __shared__ int sm[256];
  int tid = threadIdx.x;
  int base = 0;
  for (int c = 0; c < nb; c += 256) {
    int idx = c + tid;
    int t = (idx < nb) ? partial[idx] : 0;
    sm[tid] = t; __syncthreads();
    for (int o = 1; o < 256; o <<= 1) {
      int x = (tid >= o) ? sm[tid - o] : 0;
      __syncthreads();
      sm[tid] += x;
      __syncthreads();
    }
    if (idx < nb) partial[idx] = base + sm[tid] - t;
    base += sm[255];
    __syncthreads();
  }
}

__global__ void scan3_kernel(int* __restrict__ offs, const int* __restrict__ partial,
                             int n, int ET) {
  int i = blockIdx.x * blockDim.x + threadIdx.x;
  if (i < n) offs[i] += partial[i >> 10];
  if (i == 0) offs[n] = ET;
}

// ---------------- per-(partition,bucket) cursor init ----------------
__global__ void pbscan_kernel(const int* __restrict__ pbcnt, const int* __restrict__ offs,
                              int* __restrict__ pboff, int nbuck) {
  int b = blockIdx.x * blockDim.x + threadIdx.x;
  if (b >= nbuck) return;
  int cum = offs[b << NPB_SH];
  #pragma unroll
  for (int p = 0; p < NPART; ++p) {
    pboff[p * nbuck + b] = cum;
    cum += pbcnt[p * nbuck + b];
  }
}

// ---------------- sort pass 1: bin edges, XCD-partitioned cursors ----------------
__global__ void bucket_scatter(const int* __restrict__ ei, int* __restrict__ pboff,
                               unsigned int* __restrict__ pairs, int E, int ET, int nbuck) {
  int e = blockIdx.x * blockDim.x + threadIdx.x;
  if (e >= ET) return;
  int s, d;
  if (e < E) { s = ei[e]; d = ei[E + e]; }
  else       { s = e - E; d = e - E; }
  int b = d >> NPB_SH;
  int pos = atomicAdd(&pboff[(blockIdx.x & (NPART - 1)) * nbuck + b], 1);
  pairs[pos] = (unsigned)s | ((unsigned)(d & (NPB - 1)) << 27);
}

// ---------------- sort pass 2: rank within bucket via LDS, coalesced write ----------------
__global__ __launch_bounds__(256) void place_kernel(
    const unsigned int* __restrict__ pairs, const int* __restrict__ offs,
    int* __restrict__ srcs, int n) {
  __shared__ int loc[S2_CAP];
  __shared__ int lcnt[NPB];
  __shared__ int lofs[NPB + 1];
  int b = blockIdx.x;
  int node0 = b << NPB_SH;
  if (node0 >= n) return;
  int tid = threadIdx.x;
  int nloc = min(NPB, n - node0);
  if (tid < NPB) lcnt[tid] = 0;
  if (tid <= nloc) lofs[tid] = offs[node0 + tid];
  __syncthreads();
  int rbeg = lofs[0], rend = lofs[nloc];
  int len = rend - rbeg;
  if (len <= S2_CAP) {
    for (int i = tid; i < len; i += 256) {
      unsigned p = pairs[rbeg + i];
      int s = (int)(p & ((1u << 27) - 1));
      int dl = (int)(p >> 27);
      int r = atomicAdd(&lcnt[dl], 1);
      loc[lofs[dl] - rbeg + r] = s;
    }
    __syncthreads();
    for (int i = tid; i < len; i += 256) srcs[rbeg + i] = loc[i];
  } else {
    for (int i = tid; i < len; i += 256) {
      unsigned p = pairs[rbeg + i];
      int s = (int)(p & ((1u << 27) - 1));
      int dl = (int)(p >> 27);
      int r = atomicAdd(&lcnt[dl], 1);
      srcs[lofs[dl] + r] = s;
    }
  }
}

// ---------------- W1 prep: transpose to [64][256] and split into bf16 hi/lo ----------------
__global__ void wprep_kernel(const float* __restrict__ W1,
                             __bf16* __restrict__ Wt_hi, __bf16* __restrict__ Wt_lo) {
  int i = blockIdx.x * blockDim.x + threadIdx.x;   // over 256*64
  if (i >= IN_DIM * HC) return;
  int k = i >> 6, nn = i & 63;
  float f = W1[i];
  __bf16 h = (__bf16)f;
  __bf16 l = (__bf16)(f - (float)h);
  Wt_hi[nn * IN_DIM + k] = h;
  Wt_lo[nn * IN_DIM + k] = l;
}

// ---------------- layer 1 projection via MFMA (split-bf16, 3 products) ----------------
__global__ __launch_bounds__(256) void gemm1_mfma(
    const float* __restrict__ x,
    const __bf16* __restrict__ Wt_hi, const __bf16* __restrict__ Wt_lo,
    const float* __restrict__ a_s, const float* __restrict__ a_d,
    float* __restrict__ xp1, float* __restrict__ es1, float* __restrict__ ed1, int n) {
  int wave = threadIdx.x >> 6, lane = threadIdx.x & 63;
  int l15 = lane & 15, kgrp = lane >> 4;
  int rowA = blockIdx.x * 64 + wave * 16 + l15;
  bool okA = rowA < n;
  const float* xrow = x + (size_t)rowA * IN_DIM;

  f32x4 acc[4] = {};
  #pragma unroll
  for (int c = 0; c < 8; ++c) {
    int k0 = c * 32 + kgrp * 8;
    f32x4 v0 = {}, v1 = {};
    if (okA) {
      v0 = *(const f32x4*)(xrow + k0);
      v1 = *(const f32x4*)(xrow + k0 + 4);
    }
    bf16x8 ahi, alo;
    #pragma unroll
    for (int i = 0; i < 4; ++i) {
      float f0 = v0[i], f1 = v1[i];
      __bf16 h0 = (__bf16)f0, h1 = (__bf16)f1;
      ahi[i]     = h0;
      ahi[4 + i] = h1;
      alo[i]     = (__bf16)(f0 - (float)h0);
      alo[4 + i] = (__bf16)(f1 - (float)h1);
    }
    #pragma unroll
    for (int t = 0; t < 4; ++t) {
      const __bf16* wph = Wt_hi + ((t * 16 + l15) * IN_DIM + k0);
      const __bf16* wpl = Wt_lo + ((t * 16 + l15) * IN_DIM + k0);
      bf16x8 bhi = *(const bf16x8*)wph;
      bf16x8 blo = *(const bf16x8*)wpl;
      acc[t] = __builtin_amdgcn_mfma_f32_16x16x32_bf16(ahi, bhi, acc[t], 0, 0, 0);
      acc[t] = __builtin_amdgcn_mfma_f32_16x16x32_bf16(ahi, blo, acc[t], 0, 0, 0);
      acc[t] = __builtin_amdgcn_mfma_f32_16x16x32_bf16(alo, bhi, acc[t], 0, 0, 0);
    }
  }

  // epilogue: write xp1 + fused es/ed attention dots (per-head = per 16-col tile)
  int rowbase = blockIdx.x * 64 + wave * 16 + kgrp * 4;
  #pragma unroll
  for (int t = 0; t < 4; ++t) {
    float as_v = a_s[t * 16 + l15], ad_v = a_d[t * 16 + l15];
    #pragma unroll
    for (int r = 0; r < 4; ++r) {
      int row = rowbase + r;
      float v = acc[t][r];
      bool ok = row < n;
      if (ok) xp1[(size_t)row * HC + t * 16 + l15] = v;
      float ps = v * as_v, pd = v * ad_v;
      #pragma unroll
      for (int o = 1; o < 16; o <<= 1) {
        ps += __shfl_xor(ps, o, 16);
        pd += __shfl_xor(pd, o, 16);
      }
      if (ok && l15 == 0) {
        es1[row * 4 + t] = ps;
        ed1[row * 4 + t] = pd;
      }
    }
  }
}

// ---------------- layer 1 aggregation: chunked two-phase softmax ----------------
__global__ __launch_bounds__(256) void agg1_csr(
    const int* __restrict__ offs, const int* __restrict__ srcs,
    const float* __restrict__ es1, const float* __restrict__ ed1,
    const float* __restrict__ xp1, const float* __restrict__ b1,
    float* __restrict__ hout, int n) {
  __shared__ float lds[4][16 * 4 * 2];
  int wave = threadIdx.x >> 6;
  int wid = (blockIdx.x * 256 + threadIdx.x) >> 6;
  if (wid >= n) return;
  int lane = threadIdx.x & 63;
  int eidx = lane >> 2, hA = lane & 3;   // phase-A view
  int hd = lane >> 4;                     // phase-B (channel) head
  int beg = offs[wid], end = offs[wid + 1];
  float edh = ed1[wid * 4 + hA];
  float m = -INFINITY, zacc = 0.f, acc = 0.f;
  const char* xcol = (const char*)(xp1 + lane);
  float* myl = lds[wave];

  for (int e0 = beg; e0 < end; e0 += 16) {
    int cnt = min(16, end - e0);
    // ---- phase A (edge view) ----
    float v = -INFINITY;
    int s = 0;
    if (eidx < cnt) {
      s = srcs[e0 + eidx];
      v = lrelu(es1[s * 4 + hA] + edh);
    }
    float mc = v;
    mc = fmaxf(mc, __shfl_xor(mc, 4));
    mc = fmaxf(mc, __shfl_xor(mc, 8));
    mc = fmaxf(mc, __shfl_xor(mc, 16));
    mc = fmaxf(mc, __shfl_xor(mc, 32));
    float mnew = fmaxf(m, mc);
    float sc = __expf(m - mnew);          // first chunk: exp(-inf)=0
    float ex = (eidx < cnt) ? __expf(v - mnew) : 0.f;
    zacc = zacc * sc + ex;
    m = mnew;
    myl[lane * 2]     = ex;
    myl[lane * 2 + 1] = __int_as_float(s * (int)(HC * sizeof(float)));
    // ---- rescale acc (channel view) ----
    float sc_c = __shfl(sc, hd);          // lane hd holds head hd's sc
    acc *= sc_c;
    // ---- phase B (channel view) ----
    #pragma unroll 4
    for (int j = 0; j < cnt; ++j) {
      float2 ao = *(const float2*)&myl[(j * 4 + hd) * 2];
      float xv = *(const float*)(xcol + __float_as_int(ao.y));
      acc = fmaf(ao.x, xv, acc);
    }
  }

  float z = zacc;
  z += __shfl_xor(z, 4); z += __shfl_xor(z, 8);
  z += __shfl_xor(z, 16); z += __shfl_xor(z, 32);
  float zc = __shfl(z, hd);
  hout[(size_t)wid * HC + lane] = fmaxf(acc / (zc + 1e-16f) + b1[lane], 0.f);
}

// ---------------- layer 2 projection: xp2 = h @ W2, es2/ed2 dots ----------------
__global__ __launch_bounds__(256) void layer2_kernel(
    const float* __restrict__ h, const float* __restrict__ W2,
    const float* __restrict__ a_s2, const float* __restrict__ a_d2,
    float* __restrict__ xp2, float* __restrict__ es2, float* __restrict__ ed2, int n) {
  __shared__ float W2l[64 * OUT_DIM];
  __shared__ float hl[4][64];
  int tid = threadIdx.x;
  for (int i = tid; i < 64 * OUT_DIM; i += 256) W2l[i] = W2[i];
  int r = tid >> 6, j = tid & 63;
  int row = blockIdx.x * 4 + r;
  if (row < n) hl[r][j] = h[(size_t)row * 64 + j];
  __syncthreads();
  if (row >= n) return;
  float ps = 0.f, pd = 0.f;
  if (j < OUT_DIM) {
    float sum = 0.f;
    #pragma unroll 8
    for (int k = 0; k < 64; ++k) sum += hl[r][k] * W2l[k * OUT_DIM + j];
    xp2[(size_t)row * OUT_DIM + j] = sum;
    ps = sum * a_s2[j];
    pd = sum * a_d2[j];
  }
  #pragma unroll
  for (int o = 32; o; o >>= 1) {
    ps += __shfl_down(ps, o, 64);
    pd += __shfl_down(pd, o, 64);
  }
  if (j == 0) { es2[row] = ps; ed2[row] = pd; }
}

// ---------------- layer 2 aggregation: chunked two-phase softmax ----------------
__global__ __launch_bounds__(256) void agg2_csr(
    const int* __restrict__ offs, const int* __restrict__ srcs,
    const float* __restrict__ es2, const float* __restrict__ ed2,
    const float* __restrict__ xp2, const float* __restrict__ b2,
    float* __restrict__ out, int n) {
  __shared__ float lds[4][64 * 2];
  int wave = threadIdx.x >> 6;
  int wid = (blockIdx.x * 256 + threadIdx.x) >> 6;
  if (wid >= n) return;
  int lane = threadIdx.x & 63;
  int beg = offs[wid], end = offs[wid + 1];
  float edv = ed2[wid];
  float m = -INFINITY, zacc = 0.f, acc = 0.f;
  const char* xcol = (const char*)(xp2 + lane);
  float* myl = lds[wave];

  for (int e0 = beg; e0 < end; e0 += 64) {
    int cnt = min(64, end - e0);
    // ---- phase A: lanes = edges ----
    float v = -INFINITY;
    int s = 0;
    if (lane < cnt) {
      s = srcs[e0 + lane];
      v = lrelu(es2[s] + edv);
    }
    float mc = v;
    #pragma unroll
    for (int o = 1; o < 64; o <<= 1) mc = fmaxf(mc, __shfl_xor(mc, o));
    float mnew = fmaxf(m, mc);
    float sc = __expf(m - mnew);
    float ex = (lane < cnt) ? __expf(v - mnew) : 0.f;
    zacc = zacc * sc + ex;
    m = mnew;
    myl[lane * 2]     = ex;
    myl[lane * 2 + 1] = __int_as_float(s * (int)(OUT_DIM * sizeof(float)));
    acc *= sc;                              // single head: sc uniform
    // ---- phase B: lanes = channels (40 active) ----
    if (lane < OUT_DIM) {
      #pragma unroll 4
      for (int j = 0; j < cnt; ++j) {
        float2 ao = *(const float2*)&myl[j * 2];   // uniform addr -> broadcast
        float xv = *(const float*)(xcol + __float_as_int(ao.y));
        acc = fmaf(ao.x, xv, acc);
      }
    }
  }

  float z = zacc;
  #pragma unroll
  for (int o = 1; o < 64; o <<= 1) z += __shfl_xor(z, o);
  if (lane < OUT_DIM)
    out[(size_t)wid * OUT_DIM + lane] = acc / (z + 1e-16f) + b2[lane];
}

extern "C" void kernel_launch(void* const* d_in, const int* in_sizes, int n_in,
                              void* d_out, int out_size, void* d_ws, size_t ws_size,
                              hipStream_t stream) {
  const float* x    = (const float*)d_in[0];
  const int*   ei   = (const int*)d_in[1];
  const float* W1   = (const float*)d_in[2];
  const float* a_s1 = (const float*)d_in[3];
  const float* a_d1 = (const float*)d_in[4];
  const float* b1   = (const float*)d_in[5];
  const float* W2   = (const float*)d_in[6];
  const float* a_s2 = (const float*)d_in[7];
  const float* a_d2 = (const float*)d_in[8];
  const float* b2   = (const float*)d_in[9];

  int n  = in_sizes[0] / IN_DIM;
  int E  = in_sizes[1] / 2;
  int ET = E + n;
  int nbuck = (n + NPB - 1) / NPB;
  float* out = (float*)d_out;

  char* ws = (char*)d_ws;
  size_t off = 0;
  auto alloc = [&](size_t bytes) -> void* {
    void* p = ws + off;
    off = (off + bytes + 255) & ~(size_t)255;
    return p;
  };
  float*  xp1   = (float*)alloc((size_t)n * HC * 4);     // reused as xp2 later
  float*  h     = (float*)alloc((size_t)n * HC * 4);
  float*  es1   = (float*)alloc((size_t)n * 4 * 4);
  float*  ed1   = (float*)alloc((size_t)n * 4 * 4);
  float*  es2   = (float*)alloc((size_t)n * 4);
  float*  ed2   = (float*)alloc((size_t)n * 4);
  int*    deg   = (int*)alloc((size_t)n * 4);
  int*    pbcnt = (int*)alloc((size_t)NPART * nbuck * 4);
  int*    pboff = (int*)alloc((size_t)NPART * nbuck * 4);
  int*    offs  = (int*)alloc((size_t)(n + 1) * 4);
  int*    part  = (int*)alloc((size_t)1024 * 4);
  int*    srcs  = (int*)alloc((size_t)ET * 4);
  unsigned int* pairs = (unsigned int*)alloc((size_t)ET * 4);
  __bf16* Wt_hi = (__bf16*)alloc((size_t)IN_DIM * HC * 2);
  __bf16* Wt_lo = (__bf16*)alloc((size_t)IN_DIM * HC * 2);
  float*  xp2   = xp1;  // xp1 dead after agg1_csr

  int nb = (n + 1023) / 1024;   // scan blocks

  zero_kernel<<<(max(n, NPART * nbuck) + 255) / 256, 256, 0, stream>>>(
      deg, pbcnt, n, NPART * nbuck);
  count_kernel<<<(ET + 255) / 256, 256, 0, stream>>>(ei, deg, pbcnt, E, ET, nbuck);
  scan1_kernel<<<nb, 256, 0, stream>>>(deg, offs, part, n);
  scan2_kernel<<<1, 256, 0, stream>>>(part, nb);
  scan3_kernel<<<(n + 255) / 256, 256, 0, stream>>>(offs, part, n, ET);
  pbscan_kernel<<<(nbuck + 255) / 256, 256, 0, stream>>>(pbcnt, offs, pboff, nbuck);
  bucket_scatter<<<(ET + 255) / 256, 256, 0, stream>>>(ei, pboff, pairs, E, ET, nbuck);
  place_kernel<<<nbuck, 256, 0, stream>>>(pairs, offs, srcs, n);

  wprep_kernel<<<(IN_DIM * HC + 255) / 256, 256, 0, stream>>>(W1, Wt_hi, Wt_lo);
  gemm1_mfma<<<(n + 63) / 64, 256, 0, stream>>>(x, Wt_hi, Wt_lo, a_s1, a_d1,
                                                xp1, es1, ed1, n);
  agg1_csr<<<(n * 64 + 255) / 256, 256, 0, stream>>>(offs, srcs, es1, ed1, xp1, b1, h, n);
  layer2_kernel<<<(n + 3) / 4, 256, 0, stream>>>(h, W2, a_s2, a_d2, xp2, es2, ed2, n);
  agg2_csr<<<(n * 64 + 255) / 256, 256, 0, stream>>>(offs, srcs, es2, ed2, xp2, b2, out, n);
}

// Round 7
// 377.694 us; speedup vs baseline: 1.3596x; 1.3596x over previous
//
#include <hip/hip_runtime.h>
#include <hip/hip_bf16.h>

#define IN_DIM 256
#define HC     64    // H*C for layer 1
#define OUT_DIM 40
#define NEG    0.2f

#define NB_SH   8     // 256 nodes per bucket
#define NB_MASK 255
#define SRC_BITS 17   // n=100000 < 2^17
#define SRC_MASK 0x1FFFF
#define CHUNK   8192  // edges per scatter block
#define LEN_CAP 6144  // place2 LDS capacity (mean bucket len ~4450)

typedef __bf16 bf16x8 __attribute__((ext_vector_type(8)));
typedef float  f32x4  __attribute__((ext_vector_type(4)));

__device__ inline float lrelu(float v) { return fmaxf(v, NEG * v); }  // NEG<1

// ---------------- CSR 1: per-block bucket histogram (no global atomics) ----------------
__global__ __launch_bounds__(256) void hist_kernel(
    const int* __restrict__ ei, int* __restrict__ blkhist, int E, int ET, int nbuck) {
  __shared__ int hist[512];
  int tid = threadIdx.x;
  for (int i = tid; i < nbuck; i += 256) hist[i] = 0;
  __syncthreads();
  int base = blockIdx.x * CHUNK;
  #pragma unroll 4
  for (int it = 0; it < CHUNK / 256; ++it) {
    int e = base + it * 256 + tid;
    if (e < ET) {
      int d = (e < E) ? ei[E + e] : (e - E);
      atomicAdd(&hist[d >> NB_SH], 1);
    }
  }
  __syncthreads();
  for (int i = tid; i < nbuck; i += 256) blkhist[blockIdx.x * nbuck + i] = hist[i];
}

// ---------------- CSR 2: bucket totals + exclusive scan -> bucket starts ----------------
__global__ __launch_bounds__(512) void bscan_kernel(
    const int* __restrict__ blkhist, int* __restrict__ bstart,
    int* __restrict__ offs, int nblk, int nbuck, int ET, int n) {
  __shared__ int sm[512];
  int tid = threadIdx.x;
  int total = 0;
  if (tid < nbuck)
    for (int i = 0; i < nblk; ++i) total += blkhist[i * nbuck + tid];
  sm[tid] = total; __syncthreads();
  for (int o = 1; o < 512; o <<= 1) {
    int v = (tid >= o) ? sm[tid - o] : 0;
    __syncthreads();
    sm[tid] += v;
    __syncthreads();
  }
  if (tid < nbuck) bstart[tid] = sm[tid] - total;   // exclusive
  if (tid == 0) { bstart[nbuck] = ET; offs[n] = ET; }
}

// ---------------- CSR 3: per-(block,bucket) cursors via column scan ----------------
__global__ __launch_bounds__(256) void curs_kernel(
    const int* __restrict__ blkhist, const int* __restrict__ bstart,
    int* __restrict__ cur, int nblk, int nbuck) {
  __shared__ int sm[256];
  int b = blockIdx.x, tid = threadIdx.x;
  int run = bstart[b];
  for (int c = 0; c < nblk; c += 256) {
    int idx = c + tid;
    int v = (idx < nblk) ? blkhist[idx * nbuck + b] : 0;
    sm[tid] = v; __syncthreads();
    for (int o = 1; o < 256; o <<= 1) {
      int x = (tid >= o) ? sm[tid - o] : 0;
      __syncthreads();
      sm[tid] += x;
      __syncthreads();
    }
    if (idx < nblk) cur[idx * nbuck + b] = run + sm[tid] - v;
    run += sm[255];
    __syncthreads();
  }
}

// ---------------- CSR 4: LDS-sorted scatter, coalesced run writes, no atomics ----------------
__global__ __launch_bounds__(512) void scatter1_kernel(
    const int* __restrict__ ei, const int* __restrict__ cur,
    unsigned int* __restrict__ pairs, int E, int ET, int nbuck) {
  __shared__ int hs[512];      // hist -> lofs
  __shared__ int addb[512];    // cur[blk][b] - lofs[b]
  __shared__ int lcnt[512];
  __shared__ unsigned int lout[CHUNK];
  __shared__ int ldst[CHUNK];
  int tid = threadIdx.x, blk = blockIdx.x, base = blk * CHUNK;
  hs[tid] = 0; lcnt[tid] = 0;
  __syncthreads();
  #pragma unroll 4
  for (int it = 0; it < CHUNK / 512; ++it) {
    int e = base + it * 512 + tid;
    if (e < ET) {
      int d = (e < E) ? ei[E + e] : (e - E);
      atomicAdd(&hs[d >> NB_SH], 1);
    }
  }
  __syncthreads();
  int t = hs[tid];
  for (int o = 1; o < 512; o <<= 1) {
    int v = (tid >= o) ? hs[tid - o] : 0;
    __syncthreads();
    hs[tid] += v;
    __syncthreads();
  }
  int lofs = hs[tid] - t;   // exclusive
  __syncthreads();
  hs[tid] = lofs;
  addb[tid] = ((tid < nbuck) ? cur[(size_t)blk * nbuck + tid] : 0) - lofs;
  __syncthreads();
  #pragma unroll 4
  for (int it = 0; it < CHUNK / 512; ++it) {
    int e = base + it * 512 + tid;
    if (e < ET) {
      int s, d;
      if (e < E) { s = ei[e]; d = ei[E + e]; }
      else       { s = e - E; d = s; }
      int b = d >> NB_SH;
      int pos = hs[b] + atomicAdd(&lcnt[b], 1);
      lout[pos] = (unsigned)s | ((unsigned)(d & NB_MASK) << SRC_BITS);
      ldst[pos] = addb[b] + pos;
    }
  }
  __syncthreads();
  int len = min(CHUNK, ET - base);
  for (int i = tid; i < len; i += 512) pairs[ldst[i]] = lout[i];
}

// ---------------- CSR 5: per-bucket node ranking -> offs + srcs (coalesced) ----------------
__global__ __launch_bounds__(512) void place2_kernel(
    const unsigned int* __restrict__ pairs, const int* __restrict__ bstart,
    int* __restrict__ offs, int* __restrict__ srcs, int n, int nbuck) {
  __shared__ unsigned int lin[LEN_CAP];
  __shared__ unsigned int lou[LEN_CAP];
  __shared__ int lhs[256];
  __shared__ int lcnt[256];
  __shared__ int sm[512];
  int b = blockIdx.x, tid = threadIdx.x;
  int rbeg = bstart[b], rend = bstart[b + 1], len = rend - rbeg;
  int node0 = b << NB_SH;
  int nloc = min(256, n - node0);
  if (tid < 256) { lhs[tid] = 0; lcnt[tid] = 0; }
  __syncthreads();
  if (len <= LEN_CAP) {
    for (int i = tid; i < len; i += 512) {
      unsigned p = pairs[rbeg + i];
      lin[i] = p;
      atomicAdd(&lhs[(p >> SRC_BITS) & NB_MASK], 1);
    }
    __syncthreads();
    int t = (tid < 256) ? lhs[tid] : 0;
    sm[tid] = t; __syncthreads();
    for (int o = 1; o < 512; o <<= 1) {
      int v = (tid >= o) ? sm[tid - o] : 0;
      __syncthreads();
      sm[tid] += v;
      __syncthreads();
    }
    int excl = sm[tid] - t;
    if (tid < nloc) offs[node0 + tid] = rbeg + excl;
    if (tid < 256) lhs[tid] = excl;
    __syncthreads();
    for (int i = tid; i < len; i += 512) {
      unsigned p = lin[i];
      int dl = (p >> SRC_BITS) & NB_MASK;
      int pos = lhs[dl] + atomicAdd(&lcnt[dl], 1);
      lou[pos] = p & SRC_MASK;
    }
    __syncthreads();
    for (int i = tid; i < len; i += 512) srcs[rbeg + i] = (int)lou[i];
  } else {
    // fallback for oversized buckets (never hit on random graphs)
    for (int i = tid; i < len; i += 512)
      atomicAdd(&lhs[(pairs[rbeg + i] >> SRC_BITS) & NB_MASK], 1);
    __syncthreads();
    int t = (tid < 256) ? lhs[tid] : 0;
    sm[tid] = t; __syncthreads();
    for (int o = 1; o < 512; o <<= 1) {
      int v = (tid >= o) ? sm[tid - o] : 0;
      __syncthreads();
      sm[tid] += v;
      __syncthreads();
    }
    int excl = sm[tid] - t;
    if (tid < nloc) offs[node0 + tid] = rbeg + excl;
    if (tid < 256) lhs[tid] = excl;
    __syncthreads();
    for (int i = tid; i < len; i += 512) {
      unsigned p = pairs[rbeg + i];
      int dl = (p >> SRC_BITS) & NB_MASK;
      int pos = lhs[dl] + atomicAdd(&lcnt[dl], 1);
      srcs[rbeg + pos] = (int)(p & SRC_MASK);
    }
  }
}

// ---------------- W1 prep: transpose to [64][256] and split into bf16 hi/lo ----------------
__global__ void wprep_kernel(const float* __restrict__ W1,
                             __bf16* __restrict__ Wt_hi, __bf16* __restrict__ Wt_lo) {
  int i = blockIdx.x * blockDim.x + threadIdx.x;   // over 256*64
  if (i >= IN_DIM * HC) return;
  int k = i >> 6, nn = i & 63;
  float f = W1[i];
  __bf16 h = (__bf16)f;
  __bf16 l = (__bf16)(f - (float)h);
  Wt_hi[nn * IN_DIM + k] = h;
  Wt_lo[nn * IN_DIM + k] = l;
}

// ---------------- layer 1 projection via MFMA (split-bf16, 3 products) ----------------
__global__ __launch_bounds__(256) void gemm1_mfma(
    const float* __restrict__ x,
    const __bf16* __restrict__ Wt_hi, const __bf16* __restrict__ Wt_lo,
    const float* __restrict__ a_s, const float* __restrict__ a_d,
    float* __restrict__ xp1, float* __restrict__ es1, float* __restrict__ ed1, int n) {
  int wave = threadIdx.x >> 6, lane = threadIdx.x & 63;
  int l15 = lane & 15, kgrp = lane >> 4;
  int rowA = blockIdx.x * 64 + wave * 16 + l15;
  bool okA = rowA < n;
  const float* xrow = x + (size_t)rowA * IN_DIM;

  f32x4 acc[4] = {};
  #pragma unroll
  for (int c = 0; c < 8; ++c) {
    int k0 = c * 32 + kgrp * 8;
    f32x4 v0 = {}, v1 = {};
    if (okA) {
      v0 = *(const f32x4*)(xrow + k0);
      v1 = *(const f32x4*)(xrow + k0 + 4);
    }
    bf16x8 ahi, alo;
    #pragma unroll
    for (int i = 0; i < 4; ++i) {
      float f0 = v0[i], f1 = v1[i];
      __bf16 h0 = (__bf16)f0, h1 = (__bf16)f1;
      ahi[i]     = h0;
      ahi[4 + i] = h1;
      alo[i]     = (__bf16)(f0 - (float)h0);
      alo[4 + i] = (__bf16)(f1 - (float)h1);
    }
    #pragma unroll
    for (int t = 0; t < 4; ++t) {
      const __bf16* wph = Wt_hi + ((t * 16 + l15) * IN_DIM + k0);
      const __bf16* wpl = Wt_lo + ((t * 16 + l15) * IN_DIM + k0);
      bf16x8 bhi = *(const bf16x8*)wph;
      bf16x8 blo = *(const bf16x8*)wpl;
      acc[t] = __builtin_amdgcn_mfma_f32_16x16x32_bf16(ahi, bhi, acc[t], 0, 0, 0);
      acc[t] = __builtin_amdgcn_mfma_f32_16x16x32_bf16(ahi, blo, acc[t], 0, 0, 0);
      acc[t] = __builtin_amdgcn_mfma_f32_16x16x32_bf16(alo, bhi, acc[t], 0, 0, 0);
    }
  }

  // epilogue: write xp1 + fused es/ed attention dots (per-head = per 16-col tile)
  int rowbase = blockIdx.x * 64 + wave * 16 + kgrp * 4;
  #pragma unroll
  for (int t = 0; t < 4; ++t) {
    float as_v = a_s[t * 16 + l15], ad_v = a_d[t * 16 + l15];
    #pragma unroll
    for (int r = 0; r < 4; ++r) {
      int row = rowbase + r;
      float v = acc[t][r];
      bool ok = row < n;
      if (ok) xp1[(size_t)row * HC + t * 16 + l15] = v;
      float ps = v * as_v, pd = v * ad_v;
      #pragma unroll
      for (int o = 1; o < 16; o <<= 1) {
        ps += __shfl_xor(ps, o, 16);
        pd += __shfl_xor(pd, o, 16);
      }
      if (ok && l15 == 0) {
        es1[row * 4 + t] = ps;
        ed1[row * 4 + t] = pd;
      }
    }
  }
}

// ---------------- layer 1 aggregation: chunked two-phase softmax ----------------
__global__ __launch_bounds__(256) void agg1_csr(
    const int* __restrict__ offs, const int* __restrict__ srcs,
    const float* __restrict__ es1, const float* __restrict__ ed1,
    const float* __restrict__ xp1, const float* __restrict__ b1,
    float* __restrict__ hout, int n) {
  __shared__ float lds[4][16 * 4 * 2];
  int wave = threadIdx.x >> 6;
  int wid = (blockIdx.x * 256 + threadIdx.x) >> 6;
  if (wid >= n) return;
  int lane = threadIdx.x & 63;
  int eidx = lane >> 2, hA = lane & 3;   // phase-A view
  int hd = lane >> 4;                     // phase-B (channel) head
  int beg = offs[wid], end = offs[wid + 1];
  float edh = ed1[wid * 4 + hA];
  float m = -INFINITY, zacc = 0.f, acc = 0.f;
  const char* xcol = (const char*)(xp1 + lane);
  float* myl = lds[wave];

  for (int e0 = beg; e0 < end; e0 += 16) {
    int cnt = min(16, end - e0);
    // ---- phase A (edge view) ----
    float v = -INFINITY;
    int s = 0;
    if (eidx < cnt) {
      s = srcs[e0 + eidx];
      v = lrelu(es1[s * 4 + hA] + edh);
    }
    float mc = v;
    mc = fmaxf(mc, __shfl_xor(mc, 4));
    mc = fmaxf(mc, __shfl_xor(mc, 8));
    mc = fmaxf(mc, __shfl_xor(mc, 16));
    mc = fmaxf(mc, __shfl_xor(mc, 32));
    float mnew = fmaxf(m, mc);
    float sc = __expf(m - mnew);          // first chunk: exp(-inf)=0
    float ex = (eidx < cnt) ? __expf(v - mnew) : 0.f;
    zacc = zacc * sc + ex;
    m = mnew;
    myl[lane * 2]     = ex;
    myl[lane * 2 + 1] = __int_as_float(s * (int)(HC * sizeof(float)));
    // ---- rescale acc (channel view) ----
    float sc_c = __shfl(sc, hd);          // lane hd holds head hd's sc
    acc *= sc_c;
    // ---- phase B (channel view) ----
    #pragma unroll 4
    for (int j = 0; j < cnt; ++j) {
      float2 ao = *(const float2*)&myl[(j * 4 + hd) * 2];
      float xv = *(const float*)(xcol + __float_as_int(ao.y));
      acc = fmaf(ao.x, xv, acc);
    }
  }

  float z = zacc;
  z += __shfl_xor(z, 4); z += __shfl_xor(z, 8);
  z += __shfl_xor(z, 16); z += __shfl_xor(z, 32);
  float zc = __shfl(z, hd);
  hout[(size_t)wid * HC + lane] = fmaxf(acc / (zc + 1e-16f) + b1[lane], 0.f);
}

// ---------------- layer 2 projection: xp2 = h @ W2, es2/ed2 dots ----------------
__global__ __launch_bounds__(256) void layer2_kernel(
    const float* __restrict__ h, const float* __restrict__ W2,
    const float* __restrict__ a_s2, const float* __restrict__ a_d2,
    float* __restrict__ xp2, float* __restrict__ es2, float* __restrict__ ed2, int n) {
  __shared__ float W2l[64 * OUT_DIM];
  __shared__ float hl[4][64];
  int tid = threadIdx.x;
  for (int i = tid; i < 64 * OUT_DIM; i += 256) W2l[i] = W2[i];
  int r = tid >> 6, j = tid & 63;
  int row = blockIdx.x * 4 + r;
  if (row < n) hl[r][j] = h[(size_t)row * 64 + j];
  __syncthreads();
  if (row >= n) return;
  float ps = 0.f, pd = 0.f;
  if (j < OUT_DIM) {
    float sum = 0.f;
    #pragma unroll 8
    for (int k = 0; k < 64; ++k) sum += hl[r][k] * W2l[k * OUT_DIM + j];
    xp2[(size_t)row * OUT_DIM + j] = sum;
    ps = sum * a_s2[j];
    pd = sum * a_d2[j];
  }
  #pragma unroll
  for (int o = 32; o; o >>= 1) {
    ps += __shfl_down(ps, o, 64);
    pd += __shfl_down(pd, o, 64);
  }
  if (j == 0) { es2[row] = ps; ed2[row] = pd; }
}

// ---------------- layer 2 aggregation: chunked two-phase softmax ----------------
__global__ __launch_bounds__(256) void agg2_csr(
    const int* __restrict__ offs, const int* __restrict__ srcs,
    const float* __restrict__ es2, const float* __restrict__ ed2,
    const float* __restrict__ xp2, const float* __restrict__ b2,
    float* __restrict__ out, int n) {
  __shared__ float lds[4][64 * 2];
  int wave = threadIdx.x >> 6;
  int wid = (blockIdx.x * 256 + threadIdx.x) >> 6;
  if (wid >= n) return;
  int lane = threadIdx.x & 63;
  int beg = offs[wid], end = offs[wid + 1];
  float edv = ed2[wid];
  float m = -INFINITY, zacc = 0.f, acc = 0.f;
  const char* xcol = (const char*)(xp2 + lane);
  float* myl = lds[wave];

  for (int e0 = beg; e0 < end; e0 += 64) {
    int cnt = min(64, end - e0);
    // ---- phase A: lanes = edges ----
    float v = -INFINITY;
    int s = 0;
    if (lane < cnt) {
      s = srcs[e0 + lane];
      v = lrelu(es2[s] + edv);
    }
    float mc = v;
    #pragma unroll
    for (int o = 1; o < 64; o <<= 1) mc = fmaxf(mc, __shfl_xor(mc, o));
    float mnew = fmaxf(m, mc);
    float sc = __expf(m - mnew);
    float ex = (lane < cnt) ? __expf(v - mnew) : 0.f;
    zacc = zacc * sc + ex;
    m = mnew;
    myl[lane * 2]     = ex;
    myl[lane * 2 + 1] = __int_as_float(s * (int)(OUT_DIM * sizeof(float)));
    acc *= sc;                              // single head: sc uniform
    // ---- phase B: lanes = channels (40 active) ----
    if (lane < OUT_DIM) {
      #pragma unroll 4
      for (int j = 0; j < cnt; ++j) {
        float2 ao = *(const float2*)&myl[j * 2];   // uniform addr -> broadcast
        float xv = *(const float*)(xcol + __float_as_int(ao.y));
        acc = fmaf(ao.x, xv, acc);
      }
    }
  }

  float z = zacc;
  #pragma unroll
  for (int o = 1; o < 64; o <<= 1) z += __shfl_xor(z, o);
  if (lane < OUT_DIM)
    out[(size_t)wid * OUT_DIM + lane] = acc / (z + 1e-16f) + b2[lane];
}

extern "C" void kernel_launch(void* const* d_in, const int* in_sizes, int n_in,
                              void* d_out, int out_size, void* d_ws, size_t ws_size,
                              hipStream_t stream) {
  const float* x    = (const float*)d_in[0];
  const int*   ei   = (const int*)d_in[1];
  const float* W1   = (const float*)d_in[2];
  const float* a_s1 = (const float*)d_in[3];
  const float* a_d1 = (const float*)d_in[4];
  const float* b1   = (const float*)d_in[5];
  const float* W2   = (const float*)d_in[6];
  const float* a_s2 = (const float*)d_in[7];
  const float* a_d2 = (const float*)d_in[8];
  const float* b2   = (const float*)d_in[9];

  int n  = in_sizes[0] / IN_DIM;
  int E  = in_sizes[1] / 2;
  int ET = E + n;
  int nbuck = (n + 255) >> NB_SH;
  int nblk1 = (ET + CHUNK - 1) / CHUNK;
  float* out = (float*)d_out;

  char* ws = (char*)d_ws;
  size_t off = 0;
  auto alloc = [&](size_t bytes) -> void* {
    void* p = ws + off;
    off = (off + bytes + 255) & ~(size_t)255;
    return p;
  };
  float*  xp1     = (float*)alloc((size_t)n * HC * 4);   // reused as xp2 later
  float*  h       = (float*)alloc((size_t)n * HC * 4);
  float*  es1     = (float*)alloc((size_t)n * 4 * 4);
  float*  ed1     = (float*)alloc((size_t)n * 4 * 4);
  float*  es2     = (float*)alloc((size_t)n * 4);
  float*  ed2     = (float*)alloc((size_t)n * 4);
  int*    blkhist = (int*)alloc((size_t)nblk1 * nbuck * 4);
  int*    cur     = (int*)alloc((size_t)nblk1 * nbuck * 4);
  int*    bstart  = (int*)alloc((size_t)(nbuck + 1) * 4);
  int*    offs    = (int*)alloc((size_t)(n + 1) * 4);
  int*    srcs    = (int*)alloc((size_t)ET * 4);
  unsigned int* pairs = (unsigned int*)alloc((size_t)ET * 4);
  __bf16* Wt_hi   = (__bf16*)alloc((size_t)IN_DIM * HC * 2);
  __bf16* Wt_lo   = (__bf16*)alloc((size_t)IN_DIM * HC * 2);
  float*  xp2     = xp1;  // xp1 dead after agg1_csr

  hist_kernel<<<nblk1, 256, 0, stream>>>(ei, blkhist, E, ET, nbuck);
  bscan_kernel<<<1, 512, 0, stream>>>(blkhist, bstart, offs, nblk1, nbuck, ET, n);
  curs_kernel<<<nbuck, 256, 0, stream>>>(blkhist, bstart, cur, nblk1, nbuck);
  scatter1_kernel<<<nblk1, 512, 0, stream>>>(ei, cur, pairs, E, ET, nbuck);
  place2_kernel<<<nbuck, 512, 0, stream>>>(pairs, bstart, offs, srcs, n, nbuck);

  wprep_kernel<<<(IN_DIM * HC + 255) / 256, 256, 0, stream>>>(W1, Wt_hi, Wt_lo);
  gemm1_mfma<<<(n + 63) / 64, 256, 0, stream>>>(x, Wt_hi, Wt_lo, a_s1, a_d1,
                                                xp1, es1, ed1, n);
  agg1_csr<<<(n * 64 + 255) / 256, 256, 0, stream>>>(offs, srcs, es1, ed1, xp1, b1, h, n);
  layer2_kernel<<<(n + 3) / 4, 256, 0, stream>>>(h, W2, a_s2, a_d2, xp2, es2, ed2, n);
  agg2_csr<<<(n * 64 + 255) / 256, 256, 0, stream>>>(offs, srcs, es2, ed2, xp2, b2, out, n);
}